// Round 6
// baseline (279.802 us; speedup 1.0000x reference)
//
#include <hip/hip_runtime.h>

typedef unsigned short u16;
typedef u16 u16x4 __attribute__((ext_vector_type(4)));
typedef float f32x4 __attribute__((ext_vector_type(4)));
typedef __bf16 bf16x8 __attribute__((ext_vector_type(8)));

#define M_DIM 8192   // B*H = 4*2048
#define N_DIM 1024   // O
#define K_DIM 4096   // I*(D+1) = 1024*4

__device__ __forceinline__ u16 f2bf(float f) {
  unsigned u = __float_as_uint(f);
  u += 0x7FFFu + ((u >> 16) & 1u);   // round-to-nearest-even
  return (u16)(u >> 16);
}

// ---- kernel 1: x fp32 -> bf16 (lane-contiguous 16B read / 8B write) ----
__global__ __launch_bounds__(256) void k_cvt(const float* __restrict__ x,
                                             u16* __restrict__ y) {
  long i = ((long)blockIdx.x * 256 + threadIdx.x) * 4;
  f32x4 a = *(const f32x4*)(x + i);
  u16x4 r;
  r[0] = f2bf(a[0]); r[1] = f2bf(a[1]); r[2] = f2bf(a[2]); r[3] = f2bf(a[3]);
  *(u16x4*)(y + i) = r;
}

// ---- kernel 2: W2[o][i*4+d] = ws[o][i] * w[o][d], bf16 [N][K] ----
__global__ __launch_bounds__(256) void k_w2(const float* __restrict__ w,
                                            const float* __restrict__ ws,
                                            u16* __restrict__ w2) {
  int idx = blockIdx.x * 256 + threadIdx.x;  // idx = o*1024 + i
  int o = idx >> 10;
  float s = ws[idx];
  f32x4 wv = *(const f32x4*)(w + o * 4);
  u16x4 r;
  r[0] = f2bf(s * wv[0]); r[1] = f2bf(s * wv[1]);
  r[2] = f2bf(s * wv[2]); r[3] = f2bf(s * wv[3]);
  *(u16x4*)(w2 + (size_t)idx * 4) = r;
}

// ---- kernel 3: bf16 GEMM, 128x128 tile, BK=64, 512 threads (8 waves),
// XOR-swizzled LDS (R5: 0 conflicts, pinned at 85 B/cyc LDS ceiling).
// NEW: in-block split-K — waves 0-3 compute k-half 0 on a 2x2 grid of
// 64x64 wave tiles (4x4 MFMA), waves 4-7 compute k-half 1 on the SAME
// tiles. 8 frag reads per 16 MFMA = 32 FLOP/LDS-byte (was 21.3).
// Pair reduction through LDS at the end (tile LDS reused; 64 KB total,
// still 2 blocks/CU = 16 waves/CU). ----
typedef __attribute__((address_space(1))) const void gvoid_t;
typedef __attribute__((address_space(3))) void lvoid_t;
__device__ __forceinline__ void gll16(const void* g, void* l) {
  __builtin_amdgcn_global_load_lds((gvoid_t*)g, (lvoid_t*)l, 16, 0, 0);
}

__global__ __launch_bounds__(512, 4) void k_gemm(const u16* __restrict__ A,
                                                 const u16* __restrict__ Bt,
                                                 float* __restrict__ C) {
  __shared__ u16 smem[32768];        // 64 KB: [0,16K)=sA, [16K,32K)=sB,
  u16* sA = smem;                    // whole 64 KB reused for pair-reduction
  u16* sB = smem + 8192;

  const int t    = threadIdx.x;
  const int lane = t & 63;
  const int wid  = t >> 6;           // 0..7
  const int m0   = blockIdx.y * 128;
  const int n0   = blockIdx.x * 128;

  // staging (unchanged from R5): LDS slot s holds row r=s>>3, logical
  // chunk cg=(s&7)^(r&7); swizzle lives in the per-lane global address so
  // gll16's lane-contiguous LDS dest is preserved.
  const int s0 = t, s1 = t + 512;
  const int r0 = s0 >> 3, c0 = (s0 & 7) ^ (r0 & 7);
  const int r1 = s1 >> 3, c1 = (s1 & 7) ^ (r1 & 7);
  const u16* gA0 = A  + (size_t)(m0 + r0) * K_DIM + c0 * 8;
  const u16* gA1 = A  + (size_t)(m0 + r1) * K_DIM + c1 * 8;
  const u16* gB0 = Bt + (size_t)(n0 + r0) * K_DIM + c0 * 8;
  const u16* gB1 = Bt + (size_t)(n0 + r1) * K_DIM + c1 * 8;
  u16* lA0 = sA + s0 * 8;  u16* lA1 = sA + s1 * 8;
  u16* lB0 = sB + s0 * 8;  u16* lB1 = sB + s1 * 8;

  // wave -> (64x64 tile, k-half): waves 0-3 kh=0, waves 4-7 kh=1, same tiles
  const int kh = wid >> 2;           // which 32-wide k-step of the BK=64 tile
  const int wm = (wid & 1) * 64;
  const int wn = ((wid >> 1) & 1) * 64;
  const int fr = lane & 15;          // fragment row
  const int lc = lane >> 4;          // logical 16B chunk within k-step

  f32x4 acc[4][4];
#pragma unroll
  for (int i = 0; i < 4; i++)
#pragma unroll
    for (int j = 0; j < 4; j++) acc[i][j] = (f32x4){0.f, 0.f, 0.f, 0.f};

  for (int k0 = 0; k0 < K_DIM; k0 += 64) {
    gll16(gA0, lA0); gll16(gA1, lA1);
    gll16(gB0, lB0); gll16(gB1, lB1);
    gA0 += 64; gA1 += 64; gB0 += 64; gB1 += 64;
    __syncthreads();  // tiles ready

    bf16x8 af[4], bf[4];
#pragma unroll
    for (int mi = 0; mi < 4; mi++) {
      int r  = wm + mi * 16 + fr;
      int pc = (kh * 4 + lc) ^ (r & 7);
      af[mi] = *(const bf16x8*)(sA + r * 64 + pc * 8);
    }
#pragma unroll
    for (int ni = 0; ni < 4; ni++) {
      int r  = wn + ni * 16 + fr;
      int pc = (kh * 4 + lc) ^ (r & 7);
      bf[ni] = *(const bf16x8*)(sB + r * 64 + pc * 8);
    }
#pragma unroll
    for (int mi = 0; mi < 4; mi++)
#pragma unroll
      for (int ni = 0; ni < 4; ni++)
        acc[mi][ni] = __builtin_amdgcn_mfma_f32_16x16x32_bf16(
            af[mi], bf[ni], acc[mi][ni], 0, 0, 0);
    __syncthreads();  // protect LDS from next iteration's staging
  }
  // loop's trailing sync: all waves done reading tiles -> smem reusable

  // pair reduction: wave w+4 dumps acc, wave w adds. Layout per pair slot:
  // 4096 floats; (mi*4+ni) chunk of 256 floats, lane-contiguous f32x4.
  float* red = (float*)smem;  // 16384 floats = 64 KB
  if (wid >= 4) {
    float* dst = red + (wid - 4) * 4096 + lane * 4;
#pragma unroll
    for (int mi = 0; mi < 4; mi++)
#pragma unroll
      for (int ni = 0; ni < 4; ni++)
        *(f32x4*)(dst + (mi * 4 + ni) * 256) = acc[mi][ni];
  }
  __syncthreads();
  if (wid < 4) {
    float* src = red + wid * 4096 + lane * 4;
#pragma unroll
    for (int mi = 0; mi < 4; mi++)
#pragma unroll
      for (int ni = 0; ni < 4; ni++)
        acc[mi][ni] += *(const f32x4*)(src + (mi * 4 + ni) * 256);

    // C/D layout: col = lane&15, row = (lane>>4)*4 + reg
    const int cr = (lane >> 4) * 4;
    const int cc = lane & 15;
#pragma unroll
    for (int mi = 0; mi < 4; mi++)
#pragma unroll
      for (int ni = 0; ni < 4; ni++) {
        float* cp = C + (size_t)(m0 + wm + mi * 16 + cr) * N_DIM +
                    (n0 + wn + ni * 16 + cc);
#pragma unroll
        for (int r = 0; r < 4; r++) cp[(size_t)r * N_DIM] = acc[mi][ni][r];
      }
  }
}

extern "C" void kernel_launch(void* const* d_in, const int* in_sizes, int n_in,
                              void* d_out, int out_size, void* d_ws, size_t ws_size,
                              hipStream_t stream) {
  const float* x  = (const float*)d_in[0];   // (4,2048,1024,4) fp32
  const float* w  = (const float*)d_in[1];   // (1024,4) fp32
  const float* ws = (const float*)d_in[2];   // (1024,1024) fp32
  float* out = (float*)d_out;                // (4,2048,1024) fp32 = C[M][N]

  u16* xbf = (u16*)d_ws;                         // 33.5M u16 = 64 MB
  u16* w2  = xbf + (size_t)M_DIM * K_DIM;        // 4.2M u16 = 8 MB

  k_cvt<<<32768, 256, 0, stream>>>(x, xbf);
  k_w2<<<4096, 256, 0, stream>>>(w, ws, w2);

  dim3 grid(N_DIM / 128, M_DIM / 128);  // (8, 64) = 512 blocks, 2/CU
  k_gemm<<<grid, 512, 0, stream>>>(xbf, w2, out);
}